// Round 6
// baseline (173.670 us; speedup 1.0000x reference)
//
#include <hip/hip_runtime.h>
#include <hip/hip_bf16.h>

#define B_ 16
#define T_ 2048
#define C_ 384
#define H_ 64

typedef __attribute__((ext_vector_type(8))) short short8;
typedef __attribute__((ext_vector_type(4))) short short4_t;
typedef __attribute__((ext_vector_type(4))) float floatx4;
typedef __attribute__((ext_vector_type(2))) unsigned int uint2_t;
typedef __attribute__((ext_vector_type(4))) unsigned int uintx4;

#if defined(__has_builtin)
#if __has_builtin(__builtin_amdgcn_mfma_f32_16x16x16bf16_1k)
#define HAVE_MFMA16 1
#endif
#if __has_builtin(__builtin_amdgcn_global_load_lds)
#define HAVE_GLLDS 1
#endif
#endif

static __device__ __forceinline__ short f2bf(float f) {
    unsigned u = __builtin_bit_cast(unsigned, f);
    u += 0x7FFF + ((u >> 16) & 1);   // round-to-nearest-even
    return (short)(u >> 16);
}
static __device__ __forceinline__ float bf2f(short s) {
    return __builtin_bit_cast(float, ((unsigned)(unsigned short)s) << 16);
}
// packed f32x2 -> bf16x2 (RNE)
static __device__ __forceinline__ unsigned cvt_pk_bf16(float lo, float hi) {
    unsigned r;
    asm("v_cvt_pk_bf16_f32 %0, %1, %2" : "=v"(r) : "v"(lo), "v"(hi));
    return r;
}

#if defined(HAVE_GLLDS)
// async 16B/lane global->LDS; LDS dest = uniform base + lane*16B (linear).
static __device__ __forceinline__ void async_ld16(const short* g, short* lds_base) {
    __builtin_amdgcn_global_load_lds(
        (const __attribute__((address_space(1))) unsigned*)g,
        (__attribute__((address_space(3))) unsigned*)lds_base, 16, 0, 0);
}
#endif

// ---------------------------------------------------------------------------
// Kernel 0: weights fp32[C,H] -> bf16 in MFMA B-fragment order (unchanged).
// ---------------------------------------------------------------------------
__global__ void wt_kernel(const float* __restrict__ Wq, const float* __restrict__ Wk,
                          const float* __restrict__ Wv, short* __restrict__ wt2) {
    int idx = blockIdx.x * 256 + threadIdx.x;
    if (idx >= 12 * 12 * 512) return;
    int f = idx >> 9, within = idx & 511;
    int lane = within >> 3, jj = within & 7;
    int nt16 = f / 12, kc32 = f - nt16 * 12;
    int mat = nt16 >> 2, w = nt16 & 3;
    int quad = lane >> 4, l16 = lane & 15;
    int h = w * 16 + l16;
    int c = kc32 * 32 + quad * 8 + jj;
    const float* W = (mat == 0) ? Wq : ((mat == 1) ? Wk : Wv);
    wt2[idx] = f2bf(W[c * H_ + h]);
}

// ---------------------------------------------------------------------------
// Kernel 1: QKV projection, 64-row tiles (unchanged from R5).
// ---------------------------------------------------------------------------
__global__ __launch_bounds__(256) void qkv_kernel(
        const float* __restrict__ x, const short* __restrict__ wt2,
        short* __restrict__ qo, short* __restrict__ ko, short* __restrict__ vto) {
    __shared__ short xs[64 * 392];

    int b = blockIdx.y, t0 = blockIdx.x * 64;
    int tid = threadIdx.x;

    const float* src = x + (size_t)(b * T_ + t0) * C_;
    for (int i = 0; i < 24; i++) {
        int chunk = i * 256 + tid;
        int row = chunk / 96, off = (chunk % 96) * 4;
        float4 f = *(const float4*)&src[row * 384 + off];
        uint2_t u2;
        u2.x = cvt_pk_bf16(f.x, f.y);
        u2.y = cvt_pk_bf16(f.z, f.w);
        *(uint2_t*)&xs[row * 392 + off] = u2;
    }
    __syncthreads();

    int w = tid >> 6, lane = tid & 63, quad = lane >> 4, l16 = lane & 15;

    floatx4 acc[4][3];
    for (int mt = 0; mt < 4; mt++)
        for (int j = 0; j < 3; j++) acc[mt][j] = (floatx4)0.0f;

    for (int kc = 0; kc < 384; kc += 32) {
        int kc32 = kc >> 5;
        short8 a[4];
        for (int mt = 0; mt < 4; mt++)
            a[mt] = *(const short8*)&xs[(mt * 16 + l16) * 392 + kc + quad * 8];
        for (int j = 0; j < 3; j++) {
            short8 bf = *(const short8*)&wt2[(((j * 4 + w) * 12) + kc32) * 512 + lane * 8];
            for (int mt = 0; mt < 4; mt++)
                acc[mt][j] = __builtin_amdgcn_mfma_f32_16x16x32_bf16(a[mt], bf, acc[mt][j], 0, 0, 0);
        }
    }
    __syncthreads();

    {   // epilogue: q at [0,4608), k at [4608,9216), v^T at [9216,13824)
        int h = w * 16 + l16;
        for (int j = 0; j < 3; j++)
            for (int mt = 0; mt < 4; mt++)
                for (int r = 0; r < 4; r += 2) {
                    unsigned pk2 = cvt_pk_bf16(acc[mt][j][r], acc[mt][j][r + 1]);
                    int tl0 = mt * 16 + quad * 4 + r;
                    if (j == 0) {
                        xs[tl0 * 72 + h] = (short)pk2;
                        xs[(tl0 + 1) * 72 + h] = (short)(pk2 >> 16);
                    } else if (j == 1) {
                        xs[4608 + tl0 * 72 + h] = (short)pk2;
                        xs[4608 + (tl0 + 1) * 72 + h] = (short)(pk2 >> 16);
                    } else {
                        *(unsigned*)&xs[9216 + h * 72 + tl0] = pk2;
                    }
                }
    }
    __syncthreads();

    {
        int row = tid >> 3, off = (tid & 7) * 8;
        for (int i = 0; i < 2; i++) {
            int rr = row + i * 32;
            *(short8*)&qo[(size_t)(b * T_ + t0 + rr) * H_ + off] = *(const short8*)&xs[rr * 72 + off];
            *(short8*)&ko[(size_t)(b * T_ + t0 + rr) * H_ + off] = *(const short8*)&xs[4608 + rr * 72 + off];
        }
    }
    {
        int h = tid >> 2, off = (tid & 3) * 16;
        *(short8*)&vto[(size_t)(b * H_ + h) * T_ + t0 + off] = *(const short8*)&xs[9216 + h * 72 + off];
        *(short8*)&vto[(size_t)(b * H_ + h) * T_ + t0 + off + 8] = *(const short8*)&xs[9216 + h * 72 + off + 8];
    }
}

// ---------------------------------------------------------------------------
// Kernel 2a: split-K attention, 64-row q-tiles, single-buffer K/V in
// UNPADDED [64][64] LDS staged via global_load_lds (pre-swizzled global src,
// XOR unit swizzle on read). VGPR target 64 via launch_bounds(256,8) ->
// 8 blocks/CU (LDS 16.4KB), 32 waves/CU. 4 waves/block, 16 q-rows/wave.
// ---------------------------------------------------------------------------
#define SLOT_BYTES (8192 + 256)

__global__ __launch_bounds__(256, 8) void attn_seg_kernel(
        const short* __restrict__ q, const short* __restrict__ k,
        const short* __restrict__ vt, float* __restrict__ slots) {
    __shared__ short ks[64 * 64];
    __shared__ short vs[64 * 64];
#if !defined(HAVE_MFMA16)
    __shared__ short ps[4 * 16 * 72];
#endif

    int nslot = gridDim.x;
    int b = blockIdx.y, fid = nslot - 1 - (int)blockIdx.x;   // LPT: big tau first
    int tau = 0, cum = 0;
    while (cum + ((tau + 4) >> 2) <= fid) { cum += (tau + 4) >> 2; tau++; }
    int nk = tau + 1;
    int k0 = (fid - cum) * 4;
    int k1 = min(k0 + 4, nk);

    int tid = threadIdx.x, w = tid >> 6, lane = tid & 63, quad = lane >> 4, l16 = lane & 15;

    short8 aq0, aq1;
    {
        const short* qrow = q + (size_t)(b * T_ + tau * 64 + w * 16 + l16) * H_;
        aq0 = *(const short8*)&qrow[quad * 8];
        aq1 = *(const short8*)&qrow[32 + quad * 8];
    }

    floatx4 o[4];
    for (int i = 0; i < 4; i++) o[i] = (floatx4)0.0f;
    float lp = 0.f;

    const short* kb0 = k + (size_t)b * T_ * H_;
    const short* vtb = vt + (size_t)b * H_ * T_;

    const float C1 = 0.125f * 1.44269504f;
    const float C2 = 12.0f * 1.44269504f;

    // staging: per wave, 2 instrs for K (16 rows) + 2 for V; lane -> row
    // (lane>>3), 16B unit (lane&7). Global src pre-swizzled by row&7 so
    // linear LDS holds lds[row][u] = G[row][u ^ (row&7)].
    int srow_lo = lane >> 3;         // 0..7 within the 8-row group
    int uw = lane & 7;

#define STAGE_TILE(st)                                                          \
    {                                                                           \
        const short* kg = kb0 + (size_t)(st) * 64 * H_;                         \
        int s0s = (st) * 64;                                                    \
        for (int i = 0; i < 2; i++) {                                           \
            int rk = w * 16 + i * 8 + srow_lo;                                  \
            const short* gk = kg + rk * 64 + (((uw) ^ (rk & 7)) << 3);          \
            const short* gv = vtb + (size_t)rk * T_ + s0s + (((uw) ^ (rk & 7)) << 3); \
            STAGE16(gk, &ks[(w * 16 + i * 8) * 64]);                            \
            STAGE16(gv, &vs[(w * 16 + i * 8) * 64]);                            \
        }                                                                       \
    }

#if defined(HAVE_GLLDS)
#define STAGE16(g, l) async_ld16((g), (l))
#else
#define STAGE16(g, l) { short8 d_ = *(const short8*)(g); \
        *(short8*)((l) + (size_t)lane * 8) = d_; }
#endif
    // NOTE for non-GLLDS fallback: source is swizzled & dest linear — same
    // data placement as the async path.

    STAGE_TILE(k0);
    __syncthreads();

    for (int st = k0; st < k1; st++) {
        int s0 = st * 64;

        // S^T = K·Q^T : A = K-frag, B = Q-frag (operand swap).
        floatx4 sacc[4];
        for (int nt = 0; nt < 4; nt++) sacc[nt] = (floatx4)0.0f;
        __builtin_amdgcn_s_setprio(1);
        for (int nt = 0; nt < 4; nt++) {
            int row = nt * 16 + l16, sw = row & 7;
            short8 bk0 = *(const short8*)&ks[row * 64 + ((quad ^ sw) << 3)];
            short8 bk1 = *(const short8*)&ks[row * 64 + (((4 + quad) ^ sw) << 3)];
            sacc[nt] = __builtin_amdgcn_mfma_f32_16x16x32_bf16(bk0, aq0, sacc[nt], 0, 0, 0);
            sacc[nt] = __builtin_amdgcn_mfma_f32_16x16x32_bf16(bk1, aq1, sacc[nt], 0, 0, 0);
        }
        __builtin_amdgcn_s_setprio(0);

        bool diag = (st == tau);
#if defined(HAVE_MFMA16)
        short4_t pa[4];
        if (!diag) {            // wave-uniform fast path
            float ts[4];
            for (int nt = 0; nt < 4; nt++) {
                float pv[4];
                for (int r = 0; r < 4; r++)
                    pv[r] = __builtin_amdgcn_exp2f(fmaf(sacc[nt][r], C1, -C2));
                uint2_t u;
                u.x = cvt_pk_bf16(pv[0], pv[1]);
                u.y = cvt_pk_bf16(pv[2], pv[3]);
                pa[nt] = __builtin_bit_cast(short4_t, u);
                ts[nt] = (pv[0] + pv[1]) + (pv[2] + pv[3]);
            }
            lp += (ts[0] + ts[1]) + (ts[2] + ts[3]);
        } else {
            int q_idx = tau * 64 + w * 16 + l16;
            float ts[4];
            for (int nt = 0; nt < 4; nt++) {
                float pv[4];
                for (int r = 0; r < 4; r++) {
                    float pe = __builtin_amdgcn_exp2f(fmaf(sacc[nt][r], C1, -C2));
                    int s_idx = s0 + nt * 16 + quad * 4 + r;
                    pv[r] = (s_idx > q_idx) ? 0.0f : pe;
                }
                uint2_t u;
                u.x = cvt_pk_bf16(pv[0], pv[1]);
                u.y = cvt_pk_bf16(pv[2], pv[3]);
                pa[nt] = __builtin_bit_cast(short4_t, u);
                ts[nt] = (pv[0] + pv[1]) + (pv[2] + pv[3]);
            }
            lp += (ts[0] + ts[1]) + (ts[2] + ts[3]);
        }
        // O += P·V : A = P (registers), B = V-frag (swizzled read), K=16.
        __builtin_amdgcn_s_setprio(1);
        for (int nh = 0; nh < 4; nh++) {
            int row = nh * 16 + l16, sw = row & 7;
            for (int c = 0; c < 4; c++) {
                int unit = c * 2 + (quad >> 1);
                short4_t bv = *(const short4_t*)&vs[row * 64 + ((unit ^ sw) << 3) + (quad & 1) * 4];
                o[nh] = __builtin_amdgcn_mfma_f32_16x16x16bf16_1k(pa[c], bv, o[nh], 0, 0, 0);
            }
        }
        __builtin_amdgcn_s_setprio(0);
#else
        short* psw = ps + w * 16 * 72;
        short8 ap0, ap1;
        {
            int q_idx = tau * 64 + w * 16 + l16;
            for (int nt = 0; nt < 4; nt++)
                for (int r = 0; r < 4; r++) {
                    float pv = __builtin_amdgcn_exp2f(fmaf(sacc[nt][r], C1, -C2));
                    int s_idx = s0 + nt * 16 + quad * 4 + r;
                    if (diag && (s_idx > q_idx)) pv = 0.0f;
                    lp += pv;
                    psw[l16 * 72 + nt * 16 + quad * 4 + r] = f2bf(pv);
                }
            ap0 = *(const short8*)&psw[l16 * 72 + quad * 8];
            ap1 = *(const short8*)&psw[l16 * 72 + 32 + quad * 8];
        }
        for (int nh = 0; nh < 4; nh++) {
            int row = nh * 16 + l16, sw = row & 7;
            short8 bv0 = *(const short8*)&vs[row * 64 + ((quad ^ sw) << 3)];
            short8 bv1 = *(const short8*)&vs[row * 64 + (((4 + quad) ^ sw) << 3)];
            o[nh] = __builtin_amdgcn_mfma_f32_16x16x32_bf16(ap0, bv0, o[nh], 0, 0, 0);
            o[nh] = __builtin_amdgcn_mfma_f32_16x16x32_bf16(ap1, bv1, o[nh], 0, 0, 0);
        }
#endif

        if (st + 1 < k1) {
            __syncthreads();            // all waves done reading ks/vs
            STAGE_TILE(st + 1);
            __syncthreads();            // staging drained (vmcnt0 before barrier)
        }
    }

    lp += __shfl_xor(lp, 16);
    lp += __shfl_xor(lp, 32);

    char* slotb = (char*)slots + ((size_t)b * nslot + fid) * SLOT_BYTES;
    short* slotO = (short*)slotb;
    float* slotL = (float*)(slotb + 8192);

    for (int nh = 0; nh < 4; nh++)
        for (int r = 0; r < 4; r += 2) {
            unsigned pk2 = cvt_pk_bf16(o[nh][r], o[nh][r + 1]);
            slotO[(w * 16 + quad * 4 + r) * 64 + nh * 16 + l16] = (short)pk2;
            slotO[(w * 16 + quad * 4 + r + 1) * 64 + nh * 16 + l16] = (short)(pk2 >> 16);
        }
    if (quad == 0)
        slotL[w * 16 + l16] = lp;
#undef STAGE_TILE
#undef STAGE16
}

// ---------------------------------------------------------------------------
// Kernel 2b: combine for 64-row tiles. 32-row blocks (grid T/32 x B).
// ---------------------------------------------------------------------------
__global__ __launch_bounds__(256) void combine_kernel(
        const float* __restrict__ slots, int nslot, float* __restrict__ out) {
    int b = blockIdx.y, tb = blockIdx.x;        // tb in [0, 64)
    int tau = tb >> 1;
    int nseg = (tau + 4) >> 2;
    int cum = 0;
    for (int i = 0; i < tau; i++) cum += (i + 4) >> 2;
    const char* base = (const char*)slots + ((size_t)b * nslot + cum) * SLOT_BYTES;

    int tid = threadIdx.x;
    int row = (tb & 1) * 32 + (tid >> 3);       // row within the 64-row tile
    int qo = (tid & 7) * 8;                     // 8 columns per thread
    float acc[8];
    for (int i = 0; i < 8; i++) acc[i] = 0.f;
    float lsum = 0.f;
    for (int s = 0; s < nseg; s++) {
        const short* O = (const short*)(base + (size_t)s * SLOT_BYTES);
        const float* L = (const float*)(base + (size_t)s * SLOT_BYTES + 8192);
        short8 v = *(const short8*)&O[row * 64 + qo];
        uintx4 u = __builtin_bit_cast(uintx4, v);
        for (int j = 0; j < 4; j++) {
            acc[2 * j]     += __builtin_bit_cast(float, u[j] << 16);
            acc[2 * j + 1] += __builtin_bit_cast(float, u[j] & 0xFFFF0000u);
        }
        lsum += L[row];
    }
    float inv = 1.0f / lsum;
    float* op = out + (size_t)(b * T_ + tau * 64 + row) * H_ + qo;
    for (int i = 0; i < 2; i++) {
        float4 v;
        v.x = acc[i * 4 + 0] * inv; v.y = acc[i * 4 + 1] * inv;
        v.z = acc[i * 4 + 2] * inv; v.w = acc[i * 4 + 3] * inv;
        *(float4*)&op[i * 4] = v;
    }
}

// ---------------------------------------------------------------------------
// Fallback direct attention (used only if ws too small) — unchanged.
// ---------------------------------------------------------------------------
template<bool DIAG>
static __device__ __forceinline__ void attn_step(
        int s0, int t0w, int quad, int l16,
        const short* __restrict__ kbase, const short* __restrict__ vtb,
        short8 aq0, short8 aq1, short* __restrict__ psw,
        floatx4 (&o)[4], float (&lpart)[4]) {
    floatx4 sacc[4];
    for (int nt = 0; nt < 4; nt++) sacc[nt] = (floatx4)0.0f;
    for (int nt = 0; nt < 4; nt++) {
        short8 bk0 = *(const short8*)&kbase[(nt * 16 + l16) * H_ + quad * 8];
        short8 bk1 = *(const short8*)&kbase[(nt * 16 + l16) * H_ + 32 + quad * 8];
        sacc[nt] = __builtin_amdgcn_mfma_f32_16x16x32_bf16(aq0, bk0, sacc[nt], 0, 0, 0);
        sacc[nt] = __builtin_amdgcn_mfma_f32_16x16x32_bf16(aq1, bk1, sacc[nt], 0, 0, 0);
    }
    const float C1 = 0.125f * 1.44269504f;
    const float C2 = 12.0f * 1.44269504f;
    for (int nt = 0; nt < 4; nt++) {
        int s_idx = s0 + nt * 16 + l16;
        for (int r = 0; r < 4; r++) {
            float p = __builtin_amdgcn_exp2f(fmaf(sacc[nt][r], C1, -C2));
            if (DIAG && (s_idx > t0w + quad * 4 + r)) p = 0.0f;
            lpart[r] += p;
            psw[(quad * 4 + r) * 72 + nt * 16 + l16] = f2bf(p);
        }
    }
    short8 ap0 = *(const short8*)&psw[l16 * 72 + quad * 8];
    short8 ap1 = *(const short8*)&psw[l16 * 72 + 32 + quad * 8];
    for (int nh = 0; nh < 4; nh++) {
        short8 bv0 = *(const short8*)&vtb[(size_t)(nh * 16 + l16) * T_ + s0 + quad * 8];
        short8 bv1 = *(const short8*)&vtb[(size_t)(nh * 16 + l16) * T_ + s0 + 32 + quad * 8];
        o[nh] = __builtin_amdgcn_mfma_f32_16x16x32_bf16(ap0, bv0, o[nh], 0, 0, 0);
        o[nh] = __builtin_amdgcn_mfma_f32_16x16x32_bf16(ap1, bv1, o[nh], 0, 0, 0);
    }
}

__global__ __launch_bounds__(256) void attn_kernel(
        const short* __restrict__ q, const short* __restrict__ k,
        const short* __restrict__ vt, float* __restrict__ out) {
    __shared__ short ps[4 * 16 * 72];

    int b = blockIdx.y;
    int g = ((int)blockIdx.x + 4 * (b & 7)) & 31;
    int tt = (b < 8) ? g : 31 - g;
    int t0 = tt * 64;
    int tid = threadIdx.x, w = tid >> 6, lane = tid & 63, quad = lane >> 4, l16 = lane & 15;
    int t0w = t0 + w * 16;

    const short* qrow = q + (size_t)(b * T_ + t0w + l16) * H_;
    short8 aq0 = *(const short8*)&qrow[quad * 8];
    short8 aq1 = *(const short8*)&qrow[32 + quad * 8];

    floatx4 o[4];
    for (int nh = 0; nh < 4; nh++) o[nh] = (floatx4)0.0f;
    float lpart[4] = {0.f, 0.f, 0.f, 0.f};

    const short* kb0 = k + (size_t)b * T_ * H_;
    const short* vtb = vt + (size_t)b * H_ * T_;
    short* psw = ps + w * 16 * 72;

    for (int st = 0; st < tt; st++)
        attn_step<false>(st * 64, t0w, quad, l16, kb0 + (size_t)st * 64 * H_,
                         vtb, aq0, aq1, psw, o, lpart);
    attn_step<true>(tt * 64, t0w, quad, l16, kb0 + (size_t)tt * 64 * H_,
                    vtb, aq0, aq1, psw, o, lpart);

    for (int d = 1; d < 16; d <<= 1)
        for (int r = 0; r < 4; r++)
            lpart[r] += __shfl_xor(lpart[r], d, 16);

    for (int nh = 0; nh < 4; nh++)
        for (int r = 0; r < 4; r++) {
            int t = t0w + quad * 4 + r;
            out[(size_t)(b * T_ + t) * H_ + nh * 16 + l16] = o[nh][r] / lpart[r];
        }
}

// ---------------------------------------------------------------------------
extern "C" void kernel_launch(void* const* d_in, const int* in_sizes, int n_in,
                              void* d_out, int out_size, void* d_ws, size_t ws_size,
                              hipStream_t stream) {
    const float* x  = (const float*)d_in[0];
    const float* Wq = (const float*)d_in[1];
    const float* Wk = (const float*)d_in[2];
    const float* Wv = (const float*)d_in[3];

    char* ws = (char*)d_ws;
    short* qb  = (short*)(ws);                                  // 4 MB
    short* kb  = (short*)(ws + (size_t)4 * 1024 * 1024);        // 4 MB
    short* vtb = (short*)(ws + (size_t)8 * 1024 * 1024);        // 4 MB, [B][H][T]
    short* wtb = (short*)(ws + (size_t)12 * 1024 * 1024);       // 144 KB (frag order)
    float* slots = (float*)(ws + (size_t)12 * 1024 * 1024 + 256 * 1024);
    size_t base_need = (size_t)12 * 1024 * 1024 + 256 * 1024;

    wt_kernel<<<dim3(288), dim3(256), 0, stream>>>(Wq, Wk, Wv, wtb);
    qkv_kernel<<<dim3(T_ / 64, B_), dim3(256), 0, stream>>>(x, wtb, qb, kb, vtb);

    float* out = (float*)d_out;
    const int NSLOT = 144;   // sum_{tau=0}^{31} ceil((tau+1)/4)
    if (ws_size >= base_need + (size_t)B_ * NSLOT * (size_t)SLOT_BYTES) {
        attn_seg_kernel<<<dim3(NSLOT, B_), dim3(256), 0, stream>>>(qb, kb, vtb, slots);
        combine_kernel<<<dim3(T_ / 32, B_), dim3(256), 0, stream>>>(slots, NSLOT, out);
    } else {
        attn_kernel<<<dim3(T_ / 64, B_), dim3(256), 0, stream>>>(qb, kb, vtb, out);
    }
}

// Round 7
// 134.363 us; speedup vs baseline: 1.2925x; 1.2925x over previous
//
#include <hip/hip_runtime.h>
#include <hip/hip_bf16.h>

#define B_ 16
#define T_ 2048
#define C_ 384
#define H_ 64

typedef __attribute__((ext_vector_type(8))) short short8;
typedef __attribute__((ext_vector_type(4))) short short4_t;
typedef __attribute__((ext_vector_type(4))) float floatx4;
typedef __attribute__((ext_vector_type(2))) unsigned int uint2_t;
typedef __attribute__((ext_vector_type(4))) unsigned int uintx4;

#if defined(__has_builtin)
#if __has_builtin(__builtin_amdgcn_mfma_f32_16x16x16bf16_1k)
#define HAVE_MFMA16 1
#endif
#endif

static __device__ __forceinline__ short f2bf(float f) {
    unsigned u = __builtin_bit_cast(unsigned, f);
    u += 0x7FFF + ((u >> 16) & 1);   // round-to-nearest-even
    return (short)(u >> 16);
}
static __device__ __forceinline__ float bf2f(short s) {
    return __builtin_bit_cast(float, ((unsigned)(unsigned short)s) << 16);
}
// packed f32x2 -> bf16x2 (RNE)
static __device__ __forceinline__ unsigned cvt_pk_bf16(float lo, float hi) {
    unsigned r;
    asm("v_cvt_pk_bf16_f32 %0, %1, %2" : "=v"(r) : "v"(lo), "v"(hi));
    return r;
}

// ---------------------------------------------------------------------------
// Kernel 0: weights fp32[C,H] -> bf16 in MFMA B-fragment order.
// ---------------------------------------------------------------------------
__global__ void wt_kernel(const float* __restrict__ Wq, const float* __restrict__ Wk,
                          const float* __restrict__ Wv, short* __restrict__ wt2) {
    int idx = blockIdx.x * 256 + threadIdx.x;
    if (idx >= 12 * 12 * 512) return;
    int f = idx >> 9, within = idx & 511;
    int lane = within >> 3, jj = within & 7;
    int nt16 = f / 12, kc32 = f - nt16 * 12;
    int mat = nt16 >> 2, w = nt16 & 3;
    int quad = lane >> 4, l16 = lane & 15;
    int h = w * 16 + l16;
    int c = kc32 * 32 + quad * 8 + jj;
    const float* W = (mat == 0) ? Wq : ((mat == 1) ? Wk : Wv);
    wt2[idx] = f2bf(W[c * H_ + h]);
}

// ---------------------------------------------------------------------------
// Kernel 1: QKV projection, 32-row tiles (R1 version): 1024 blocks ->
// 4 blocks/CU resident (vs 2 for 64-row tiles) — grid-level TLP doubled.
// ---------------------------------------------------------------------------
__global__ __launch_bounds__(256) void qkv_kernel(
        const float* __restrict__ x, const short* __restrict__ wt2,
        short* __restrict__ qo, short* __restrict__ ko, short* __restrict__ vto) {
    __shared__ short xs[32 * 392];

    int b = blockIdx.y, t0 = blockIdx.x * 32;
    int tid = threadIdx.x;

    const float* src = x + (size_t)(b * T_ + t0) * C_;
    for (int i = 0; i < 12; i++) {
        int chunk = i * 256 + tid;
        int row = chunk / 96, off = (chunk % 96) * 4;
        float4 f = *(const float4*)&src[row * 384 + off];
        uint2_t u2;
        u2.x = cvt_pk_bf16(f.x, f.y);
        u2.y = cvt_pk_bf16(f.z, f.w);
        *(uint2_t*)&xs[row * 392 + off] = u2;
    }
    __syncthreads();

    int w = tid >> 6, lane = tid & 63, quad = lane >> 4, l16 = lane & 15;

    floatx4 acc[2][3];
    for (int mt = 0; mt < 2; mt++)
        for (int j = 0; j < 3; j++) acc[mt][j] = (floatx4)0.0f;

    for (int kc = 0; kc < 384; kc += 32) {
        int kc32 = kc >> 5;
        short8 a0 = *(const short8*)&xs[l16 * 392 + kc + quad * 8];
        short8 a1 = *(const short8*)&xs[(16 + l16) * 392 + kc + quad * 8];
        for (int j = 0; j < 3; j++) {
            short8 bf = *(const short8*)&wt2[(((j * 4 + w) * 12) + kc32) * 512 + lane * 8];
            acc[0][j] = __builtin_amdgcn_mfma_f32_16x16x32_bf16(a0, bf, acc[0][j], 0, 0, 0);
            acc[1][j] = __builtin_amdgcn_mfma_f32_16x16x32_bf16(a1, bf, acc[1][j], 0, 0, 0);
        }
    }
    __syncthreads();

    {
        int h = w * 16 + l16;
        for (int j = 0; j < 3; j++)
            for (int mt = 0; mt < 2; mt++)
                for (int r = 0; r < 4; r += 2) {
                    unsigned pk2 = cvt_pk_bf16(acc[mt][j][r], acc[mt][j][r + 1]);
                    int tl0 = mt * 16 + quad * 4 + r;
                    if (j == 0) {
                        xs[tl0 * 72 + h] = (short)pk2;
                        xs[(tl0 + 1) * 72 + h] = (short)(pk2 >> 16);
                    } else if (j == 1) {
                        xs[2304 + tl0 * 72 + h] = (short)pk2;
                        xs[2304 + (tl0 + 1) * 72 + h] = (short)(pk2 >> 16);
                    } else {
                        // adjacent tl slots -> single 32-bit LDS store (tl0 even)
                        *(unsigned*)&xs[4608 + h * 40 + tl0] = pk2;
                    }
                }
    }
    __syncthreads();

    {
        int row = tid >> 3, off = (tid & 7) * 8;
        *(short8*)&qo[(size_t)(b * T_ + t0 + row) * H_ + off] = *(const short8*)&xs[row * 72 + off];
        *(short8*)&ko[(size_t)(b * T_ + t0 + row) * H_ + off] = *(const short8*)&xs[2304 + row * 72 + off];
    }
    {
        int h = tid >> 2, off = (tid & 3) * 8;
        *(short8*)&vto[(size_t)(b * H_ + h) * T_ + t0 + off] = *(const short8*)&xs[4608 + h * 40 + off];
    }
}

// ---------------------------------------------------------------------------
// Kernel 2a: split-K attention, 128-row q-tiles, double-buffered K/V staging
// (R5 structure, 127.7 µs config: natural VGPR=84, 4 blocks/CU — do NOT
// force min-waves; 8 waves/SIMD needs <=64 unified VGPR+AGPR which the
// 32-AGPR accumulator working set makes infeasible — R4/R6 spills).
// LPT dispatch: long segments (big tt) first.
// ---------------------------------------------------------------------------
#define KVSZ (64 * 72)
#define SLOT_BYTES (16384 + 512)

__global__ __launch_bounds__(256) void attn_seg_kernel(
        const short* __restrict__ q, const short* __restrict__ k,
        const short* __restrict__ vt, float* __restrict__ slots) {
    __shared__ short ks[2 * KVSZ];
    __shared__ short vs[2 * KVSZ];
#if !defined(HAVE_MFMA16)
    __shared__ short ps[4 * 16 * 72];
#endif

    int nslot = gridDim.x;
    int b = blockIdx.y, fid = nslot - 1 - (int)blockIdx.x;   // LPT: long segments first
    int tt = 0, cum = 0;
    while (cum + ((2 * tt + 5) >> 2) <= fid) { cum += (2 * tt + 5) >> 2; tt++; }
    int nk = 2 * tt + 2;
    int k0 = (fid - cum) * 4;
    int k1 = min(k0 + 4, nk);

    int tid = threadIdx.x, w = tid >> 6, lane = tid & 63, quad = lane >> 4, l16 = lane & 15;
    int trow0 = tt * 128 + w * 32;

    short8 aq[2][2];
    for (int mt = 0; mt < 2; mt++) {
        const short* qrow = q + (size_t)(b * T_ + trow0 + mt * 16 + l16) * H_;
        aq[mt][0] = *(const short8*)&qrow[quad * 8];
        aq[mt][1] = *(const short8*)&qrow[32 + quad * 8];
    }

    floatx4 o[2][4];
    for (int mt = 0; mt < 2; mt++)
        for (int i = 0; i < 4; i++) o[mt][i] = (floatx4)0.0f;
    float lp[2] = {0.f, 0.f};

    const short* kb0 = k + (size_t)b * T_ * H_;
    const short* vtb = vt + (size_t)b * H_ * T_;

    int srow = tid >> 3, soff = (tid & 7) * 8;
    const float C1 = 0.125f * 1.44269504f;
    const float C2 = 12.0f * 1.44269504f;

    {   // preload first tile into buffer 0
        const short* kg = kb0 + (size_t)k0 * 64 * H_;
        const short* vg = vtb + k0 * 64;
        *(short8*)&ks[srow * 72 + soff] = *(const short8*)&kg[srow * H_ + soff];
        *(short8*)&ks[(srow + 32) * 72 + soff] = *(const short8*)&kg[(srow + 32) * H_ + soff];
        *(short8*)&vs[srow * 72 + soff] = *(const short8*)&vg[(size_t)srow * T_ + soff];
        *(short8*)&vs[(srow + 32) * 72 + soff] = *(const short8*)&vg[(size_t)(srow + 32) * T_ + soff];
    }
    __syncthreads();

    int p = 0;
    for (int st = k0; st < k1; st++) {
        bool more = (st + 1 < k1);
        short8 pk0, pk1, pv0, pv1;
        if (more) {
            const short* kg = kb0 + (size_t)(st + 1) * 64 * H_;
            const short* vg = vtb + (st + 1) * 64;
            pk0 = *(const short8*)&kg[srow * H_ + soff];
            pk1 = *(const short8*)&kg[(srow + 32) * H_ + soff];
            pv0 = *(const short8*)&vg[(size_t)srow * T_ + soff];
            pv1 = *(const short8*)&vg[(size_t)(srow + 32) * T_ + soff];
        }
        const short* ksp = ks + p * KVSZ;
        const short* vsp = vs + p * KVSZ;
        int s0 = st * 64;

        // S^T = K·Q^T : A = K-frag, B = Q-frag (operand swap).
        floatx4 sacc[2][4];
        for (int mt = 0; mt < 2; mt++)
            for (int nt = 0; nt < 4; nt++) sacc[mt][nt] = (floatx4)0.0f;
        __builtin_amdgcn_s_setprio(1);
        for (int nt = 0; nt < 4; nt++) {
            short8 bk0 = *(const short8*)&ksp[(nt * 16 + l16) * 72 + quad * 8];
            short8 bk1 = *(const short8*)&ksp[(nt * 16 + l16) * 72 + 32 + quad * 8];
            sacc[0][nt] = __builtin_amdgcn_mfma_f32_16x16x32_bf16(bk0, aq[0][0], sacc[0][nt], 0, 0, 0);
            sacc[0][nt] = __builtin_amdgcn_mfma_f32_16x16x32_bf16(bk1, aq[0][1], sacc[0][nt], 0, 0, 0);
            sacc[1][nt] = __builtin_amdgcn_mfma_f32_16x16x32_bf16(bk0, aq[1][0], sacc[1][nt], 0, 0, 0);
            sacc[1][nt] = __builtin_amdgcn_mfma_f32_16x16x32_bf16(bk1, aq[1][1], sacc[1][nt], 0, 0, 0);
        }
        __builtin_amdgcn_s_setprio(0);

        bool diag = (st >= 2 * tt);
#if defined(HAVE_MFMA16)
        short4_t pa[2][4];
        if (!diag) {            // wave-uniform fast path: no per-element mask
            for (int mt = 0; mt < 2; mt++) {
                float ts[4];
                for (int nt = 0; nt < 4; nt++) {
                    float pv[4];
                    for (int r = 0; r < 4; r++)
                        pv[r] = __builtin_amdgcn_exp2f(fmaf(sacc[mt][nt][r], C1, -C2));
                    uint2_t u;
                    u.x = cvt_pk_bf16(pv[0], pv[1]);
                    u.y = cvt_pk_bf16(pv[2], pv[3]);
                    pa[mt][nt] = __builtin_bit_cast(short4_t, u);
                    ts[nt] = (pv[0] + pv[1]) + (pv[2] + pv[3]);
                }
                lp[mt] += (ts[0] + ts[1]) + (ts[2] + ts[3]);
            }
        } else {
            for (int mt = 0; mt < 2; mt++) {
                int q_idx = trow0 + mt * 16 + l16;
                float ts[4];
                for (int nt = 0; nt < 4; nt++) {
                    float pv[4];
                    for (int r = 0; r < 4; r++) {
                        float pe = __builtin_amdgcn_exp2f(fmaf(sacc[mt][nt][r], C1, -C2));
                        int s_idx = s0 + nt * 16 + quad * 4 + r;
                        pv[r] = (s_idx > q_idx) ? 0.0f : pe;
                    }
                    uint2_t u;
                    u.x = cvt_pk_bf16(pv[0], pv[1]);
                    u.y = cvt_pk_bf16(pv[2], pv[3]);
                    pa[mt][nt] = __builtin_bit_cast(short4_t, u);
                    ts[nt] = (pv[0] + pv[1]) + (pv[2] + pv[3]);
                }
                lp[mt] += (ts[0] + ts[1]) + (ts[2] + ts[3]);
            }
        }
        // O += P·V : A = P (registers), B = V-frag, K=16 MFMA.
        __builtin_amdgcn_s_setprio(1);
        for (int nh = 0; nh < 4; nh++) {
            const short* vrow = &vsp[(nh * 16 + l16) * 72 + quad * 4];
            for (int c = 0; c < 4; c++) {
                short4_t bv = *(const short4_t*)&vrow[c * 16];
                o[0][nh] = __builtin_amdgcn_mfma_f32_16x16x16bf16_1k(pa[0][c], bv, o[0][nh], 0, 0, 0);
                o[1][nh] = __builtin_amdgcn_mfma_f32_16x16x16bf16_1k(pa[1][c], bv, o[1][nh], 0, 0, 0);
            }
        }
        __builtin_amdgcn_s_setprio(0);
#else
        short* psw = ps + w * 16 * 72;
        short8 ap[2][2];
        for (int mt = 0; mt < 2; mt++) {
            int q_idx = trow0 + mt * 16 + l16;
            for (int nt = 0; nt < 4; nt++)
                for (int r = 0; r < 4; r++) {
                    float pv = __builtin_amdgcn_exp2f(fmaf(sacc[mt][nt][r], C1, -C2));
                    int s_idx = s0 + nt * 16 + quad * 4 + r;
                    if (diag && (s_idx > q_idx)) pv = 0.0f;
                    lp[mt] += pv;
                    psw[l16 * 72 + nt * 16 + quad * 4 + r] = f2bf(pv);
                }
            ap[mt][0] = *(const short8*)&psw[l16 * 72 + quad * 8];
            ap[mt][1] = *(const short8*)&psw[l16 * 72 + 32 + quad * 8];
        }
        for (int nh = 0; nh < 4; nh++) {
            short8 bv0 = *(const short8*)&vsp[(nh * 16 + l16) * 72 + quad * 8];
            short8 bv1 = *(const short8*)&vsp[(nh * 16 + l16) * 72 + 32 + quad * 8];
            o[0][nh] = __builtin_amdgcn_mfma_f32_16x16x32_bf16(ap[0][0], bv0, o[0][nh], 0, 0, 0);
            o[0][nh] = __builtin_amdgcn_mfma_f32_16x16x32_bf16(ap[0][1], bv1, o[0][nh], 0, 0, 0);
            o[1][nh] = __builtin_amdgcn_mfma_f32_16x16x32_bf16(ap[1][0], bv0, o[1][nh], 0, 0, 0);
            o[1][nh] = __builtin_amdgcn_mfma_f32_16x16x32_bf16(ap[1][1], bv1, o[1][nh], 0, 0, 0);
        }
#endif

        if (more) {
            short* kd = ks + (1 - p) * KVSZ;
            short* vd = vs + (1 - p) * KVSZ;
            *(short8*)&kd[srow * 72 + soff] = pk0;
            *(short8*)&kd[(srow + 32) * 72 + soff] = pk1;
            *(short8*)&vd[srow * 72 + soff] = pv0;
            *(short8*)&vd[(srow + 32) * 72 + soff] = pv1;
            __syncthreads();
            p ^= 1;
        }
    }

    for (int mt = 0; mt < 2; mt++) {
        lp[mt] += __shfl_xor(lp[mt], 16);
        lp[mt] += __shfl_xor(lp[mt], 32);
    }

    char* slotb = (char*)slots + ((size_t)b * nslot + fid) * SLOT_BYTES;
    short* slotO = (short*)slotb;
    float* slotL = (float*)(slotb + 16384);

    for (int mt = 0; mt < 2; mt++)
        for (int nh = 0; nh < 4; nh++)
            for (int r = 0; r < 4; r += 2) {
                unsigned pk2 = cvt_pk_bf16(o[mt][nh][r], o[mt][nh][r + 1]);
                slotO[(w * 32 + mt * 16 + quad * 4 + r) * 64 + nh * 16 + l16] = (short)pk2;
                slotO[(w * 32 + mt * 16 + quad * 4 + r + 1) * 64 + nh * 16 + l16] = (short)(pk2 >> 16);
            }
    if (quad == 0)
        for (int mt = 0; mt < 2; mt++)
            slotL[w * 32 + mt * 16 + l16] = lp[mt];
}

// ---------------------------------------------------------------------------
// Kernel 2b: combine. 32-row blocks (grid T/32 x B = 1024 blocks).
// ---------------------------------------------------------------------------
__global__ __launch_bounds__(256) void combine_kernel(
        const float* __restrict__ slots, int nslot, float* __restrict__ out) {
    int b = blockIdx.y, tb = blockIdx.x;        // tb in [0, 64)
    int tt = tb >> 2;
    int nseg = (2 * tt + 5) >> 2;
    int cum = 0;
    for (int i = 0; i < tt; i++) cum += (2 * i + 5) >> 2;
    const char* base = (const char*)slots + ((size_t)b * nslot + cum) * SLOT_BYTES;

    int tid = threadIdx.x;
    int row = (tb & 3) * 32 + (tid >> 3);       // row within the 128-row tile
    int qo = (tid & 7) * 8;                     // 8 columns per thread
    float acc[8];
    for (int i = 0; i < 8; i++) acc[i] = 0.f;
    float lsum = 0.f;
    for (int s = 0; s < nseg; s++) {
        const short* O = (const short*)(base + (size_t)s * SLOT_BYTES);
        const float* L = (const float*)(base + (size_t)s * SLOT_BYTES + 16384);
        short8 v = *(const short8*)&O[row * 64 + qo];
        uintx4 u = __builtin_bit_cast(uintx4, v);
        for (int j = 0; j < 4; j++) {
            acc[2 * j]     += __builtin_bit_cast(float, u[j] << 16);
            acc[2 * j + 1] += __builtin_bit_cast(float, u[j] & 0xFFFF0000u);
        }
        lsum += L[row];
    }
    float inv = 1.0f / lsum;
    float* op = out + (size_t)(b * T_ + tt * 128 + row) * H_ + qo;
    for (int i = 0; i < 2; i++) {
        float4 v;
        v.x = acc[i * 4 + 0] * inv; v.y = acc[i * 4 + 1] * inv;
        v.z = acc[i * 4 + 2] * inv; v.w = acc[i * 4 + 3] * inv;
        *(float4*)&op[i * 4] = v;
    }
}

// ---------------------------------------------------------------------------
// Fallback direct attention (used only if ws too small) — unchanged.
// ---------------------------------------------------------------------------
template<bool DIAG>
static __device__ __forceinline__ void attn_step(
        int s0, int t0w, int quad, int l16,
        const short* __restrict__ kbase, const short* __restrict__ vtb,
        short8 aq0, short8 aq1, short* __restrict__ psw,
        floatx4 (&o)[4], float (&lpart)[4]) {
    floatx4 sacc[4];
    for (int nt = 0; nt < 4; nt++) sacc[nt] = (floatx4)0.0f;
    for (int nt = 0; nt < 4; nt++) {
        short8 bk0 = *(const short8*)&kbase[(nt * 16 + l16) * H_ + quad * 8];
        short8 bk1 = *(const short8*)&kbase[(nt * 16 + l16) * H_ + 32 + quad * 8];
        sacc[nt] = __builtin_amdgcn_mfma_f32_16x16x32_bf16(aq0, bk0, sacc[nt], 0, 0, 0);
        sacc[nt] = __builtin_amdgcn_mfma_f32_16x16x32_bf16(aq1, bk1, sacc[nt], 0, 0, 0);
    }
    const float C1 = 0.125f * 1.44269504f;
    const float C2 = 12.0f * 1.44269504f;
    for (int nt = 0; nt < 4; nt++) {
        int s_idx = s0 + nt * 16 + l16;
        for (int r = 0; r < 4; r++) {
            float p = __builtin_amdgcn_exp2f(fmaf(sacc[nt][r], C1, -C2));
            if (DIAG && (s_idx > t0w + quad * 4 + r)) p = 0.0f;
            lpart[r] += p;
            psw[(quad * 4 + r) * 72 + nt * 16 + l16] = f2bf(p);
        }
    }
    short8 ap0 = *(const short8*)&psw[l16 * 72 + quad * 8];
    short8 ap1 = *(const short8*)&psw[l16 * 72 + 32 + quad * 8];
    for (int nh = 0; nh < 4; nh++) {
        short8 bv0 = *(const short8*)&vtb[(size_t)(nh * 16 + l16) * T_ + s0 + quad * 8];
        short8 bv1 = *(const short8*)&vtb[(size_t)(nh * 16 + l16) * T_ + s0 + 32 + quad * 8];
        o[nh] = __builtin_amdgcn_mfma_f32_16x16x32_bf16(ap0, bv0, o[nh], 0, 0, 0);
        o[nh] = __builtin_amdgcn_mfma_f32_16x16x32_bf16(ap1, bv1, o[nh], 0, 0, 0);
    }
}

__global__ __launch_bounds__(256) void attn_kernel(
        const short* __restrict__ q, const short* __restrict__ k,
        const short* __restrict__ vt, float* __restrict__ out) {
    __shared__ short ps[4 * 16 * 72];

    int b = blockIdx.y;
    int g = ((int)blockIdx.x + 4 * (b & 7)) & 31;
    int tt = (b < 8) ? g : 31 - g;
    int t0 = tt * 64;
    int tid = threadIdx.x, w = tid >> 6, lane = tid & 63, quad = lane >> 4, l16 = lane & 15;
    int t0w = t0 + w * 16;

    const short* qrow = q + (size_t)(b * T_ + t0w + l16) * H_;
    short8 aq0 = *(const short8*)&qrow[quad * 8];
    short8 aq1 = *(const short8*)&qrow[32 + quad * 8];

    floatx4 o[4];
    for (int nh = 0; nh < 4; nh++) o[nh] = (floatx4)0.0f;
    float lpart[4] = {0.f, 0.f, 0.f, 0.f};

    const short* kb0 = k + (size_t)b * T_ * H_;
    const short* vtb = vt + (size_t)b * H_ * T_;
    short* psw = ps + w * 16 * 72;

    for (int st = 0; st < tt; st++)
        attn_step<false>(st * 64, t0w, quad, l16, kb0 + (size_t)st * 64 * H_,
                         vtb, aq0, aq1, psw, o, lpart);
    attn_step<true>(tt * 64, t0w, quad, l16, kb0 + (size_t)tt * 64 * H_,
                    vtb, aq0, aq1, psw, o, lpart);

    for (int d = 1; d < 16; d <<= 1)
        for (int r = 0; r < 4; r++)
            lpart[r] += __shfl_xor(lpart[r], d, 16);

    for (int nh = 0; nh < 4; nh++)
        for (int r = 0; r < 4; r++) {
            int t = t0w + quad * 4 + r;
            out[(size_t)(b * T_ + t) * H_ + nh * 16 + l16] = o[nh][r] / lpart[r];
        }
}

// ---------------------------------------------------------------------------
extern "C" void kernel_launch(void* const* d_in, const int* in_sizes, int n_in,
                              void* d_out, int out_size, void* d_ws, size_t ws_size,
                              hipStream_t stream) {
    const float* x  = (const float*)d_in[0];
    const float* Wq = (const float*)d_in[1];
    const float* Wk = (const float*)d_in[2];
    const float* Wv = (const float*)d_in[3];

    char* ws = (char*)d_ws;
    short* qb  = (short*)(ws);                                  // 4 MB
    short* kb  = (short*)(ws + (size_t)4 * 1024 * 1024);        // 4 MB
    short* vtb = (short*)(ws + (size_t)8 * 1024 * 1024);        // 4 MB, [B][H][T]
    short* wtb = (short*)(ws + (size_t)12 * 1024 * 1024);       // 144 KB (frag order)
    float* slots = (float*)(ws + (size_t)12 * 1024 * 1024 + 256 * 1024);
    size_t base_need = (size_t)12 * 1024 * 1024 + 256 * 1024;

    wt_kernel<<<dim3(288), dim3(256), 0, stream>>>(Wq, Wk, Wv, wtb);
    qkv_kernel<<<dim3(T_ / 32, B_), dim3(256), 0, stream>>>(x, wtb, qb, kb, vtb);

    float* out = (float*)d_out;
    const int NSLOT = 72;   // sum_{tt=0}^{15} ceil((2tt+2)/4)
    if (ws_size >= base_need + (size_t)B_ * NSLOT * (size_t)SLOT_BYTES) {
        attn_seg_kernel<<<dim3(NSLOT, B_), dim3(256), 0, stream>>>(qb, kb, vtb, slots);
        combine_kernel<<<dim3(T_ / 32, B_), dim3(256), 0, stream>>>(slots, NSLOT, out);
    } else {
        attn_kernel<<<dim3(T_ / 64, B_), dim3(256), 0, stream>>>(qb, kb, vtb, out);
    }
}

// Round 8
// 127.651 us; speedup vs baseline: 1.3605x; 1.0526x over previous
//
#include <hip/hip_runtime.h>
#include <hip/hip_bf16.h>

#define B_ 16
#define T_ 2048
#define C_ 384
#define H_ 64

typedef __attribute__((ext_vector_type(8))) short short8;
typedef __attribute__((ext_vector_type(4))) short short4_t;
typedef __attribute__((ext_vector_type(4))) float floatx4;
typedef __attribute__((ext_vector_type(2))) unsigned int uint2_t;
typedef __attribute__((ext_vector_type(4))) unsigned int uintx4;

#if defined(__has_builtin)
#if __has_builtin(__builtin_amdgcn_mfma_f32_16x16x16bf16_1k)
#define HAVE_MFMA16 1
#endif
#endif

static __device__ __forceinline__ short f2bf(float f) {
    unsigned u = __builtin_bit_cast(unsigned, f);
    u += 0x7FFF + ((u >> 16) & 1);   // round-to-nearest-even
    return (short)(u >> 16);
}
static __device__ __forceinline__ float bf2f(short s) {
    return __builtin_bit_cast(float, ((unsigned)(unsigned short)s) << 16);
}
// packed f32x2 -> bf16x2 (RNE)
static __device__ __forceinline__ unsigned cvt_pk_bf16(float lo, float hi) {
    unsigned r;
    asm("v_cvt_pk_bf16_f32 %0, %1, %2" : "=v"(r) : "v"(lo), "v"(hi));
    return r;
}

// ---------------------------------------------------------------------------
// Kernel 0: weights fp32[C,H] -> bf16 in MFMA B-fragment order.
// ---------------------------------------------------------------------------
__global__ void wt_kernel(const float* __restrict__ Wq, const float* __restrict__ Wk,
                          const float* __restrict__ Wv, short* __restrict__ wt2) {
    int idx = blockIdx.x * 256 + threadIdx.x;
    if (idx >= 12 * 12 * 512) return;
    int f = idx >> 9, within = idx & 511;
    int lane = within >> 3, jj = within & 7;
    int nt16 = f / 12, kc32 = f - nt16 * 12;
    int mat = nt16 >> 2, w = nt16 & 3;
    int quad = lane >> 4, l16 = lane & 15;
    int h = w * 16 + l16;
    int c = kc32 * 32 + quad * 8 + jj;
    const float* W = (mat == 0) ? Wq : ((mat == 1) ? Wk : Wv);
    wt2[idx] = f2bf(W[c * H_ + h]);
}

// ---------------------------------------------------------------------------
// Kernel 1: QKV projection, 64-row tiles (B-fragments reused across 4 MFMAs;
// R7 A/B proved 32-row tiles are ~6 µs slower — wt2 L2 traffic dominates).
// ---------------------------------------------------------------------------
__global__ __launch_bounds__(256) void qkv_kernel(
        const float* __restrict__ x, const short* __restrict__ wt2,
        short* __restrict__ qo, short* __restrict__ ko, short* __restrict__ vto) {
    __shared__ short xs[64 * 392];

    int b = blockIdx.y, t0 = blockIdx.x * 64;
    int tid = threadIdx.x;

    const float* src = x + (size_t)(b * T_ + t0) * C_;
    for (int i = 0; i < 24; i++) {
        int chunk = i * 256 + tid;
        int row = chunk / 96, off = (chunk % 96) * 4;
        float4 f = *(const float4*)&src[row * 384 + off];
        uint2_t u2;
        u2.x = cvt_pk_bf16(f.x, f.y);
        u2.y = cvt_pk_bf16(f.z, f.w);
        *(uint2_t*)&xs[row * 392 + off] = u2;
    }
    __syncthreads();

    int w = tid >> 6, lane = tid & 63, quad = lane >> 4, l16 = lane & 15;

    floatx4 acc[4][3];
    for (int mt = 0; mt < 4; mt++)
        for (int j = 0; j < 3; j++) acc[mt][j] = (floatx4)0.0f;

    for (int kc = 0; kc < 384; kc += 32) {
        int kc32 = kc >> 5;
        short8 a[4];
        for (int mt = 0; mt < 4; mt++)
            a[mt] = *(const short8*)&xs[(mt * 16 + l16) * 392 + kc + quad * 8];
        for (int j = 0; j < 3; j++) {
            short8 bf = *(const short8*)&wt2[(((j * 4 + w) * 12) + kc32) * 512 + lane * 8];
            for (int mt = 0; mt < 4; mt++)
                acc[mt][j] = __builtin_amdgcn_mfma_f32_16x16x32_bf16(a[mt], bf, acc[mt][j], 0, 0, 0);
        }
    }
    __syncthreads();

    {   // epilogue: q at [0,4608), k at [4608,9216), v^T at [9216,13824)
        int h = w * 16 + l16;
        for (int j = 0; j < 3; j++)
            for (int mt = 0; mt < 4; mt++)
                for (int r = 0; r < 4; r += 2) {
                    unsigned pk2 = cvt_pk_bf16(acc[mt][j][r], acc[mt][j][r + 1]);
                    int tl0 = mt * 16 + quad * 4 + r;
                    if (j == 0) {
                        xs[tl0 * 72 + h] = (short)pk2;
                        xs[(tl0 + 1) * 72 + h] = (short)(pk2 >> 16);
                    } else if (j == 1) {
                        xs[4608 + tl0 * 72 + h] = (short)pk2;
                        xs[4608 + (tl0 + 1) * 72 + h] = (short)(pk2 >> 16);
                    } else {
                        *(unsigned*)&xs[9216 + h * 72 + tl0] = pk2;
                    }
                }
    }
    __syncthreads();

    {
        int row = tid >> 3, off = (tid & 7) * 8;
        for (int i = 0; i < 2; i++) {
            int rr = row + i * 32;
            *(short8*)&qo[(size_t)(b * T_ + t0 + rr) * H_ + off] = *(const short8*)&xs[rr * 72 + off];
            *(short8*)&ko[(size_t)(b * T_ + t0 + rr) * H_ + off] = *(const short8*)&xs[4608 + rr * 72 + off];
        }
    }
    {
        int h = tid >> 2, off = (tid & 3) * 16;
        *(short8*)&vto[(size_t)(b * H_ + h) * T_ + t0 + off] = *(const short8*)&xs[9216 + h * 72 + off];
        *(short8*)&vto[(size_t)(b * H_ + h) * T_ + t0 + off + 8] = *(const short8*)&xs[9216 + h * 72 + off + 8];
    }
}

// ---------------------------------------------------------------------------
// Kernel 2a: split-K attention, 128-row q-tiles, double-buffered K/V staging
// (R5 config, 127.7 µs: natural VGPR=84, 4 blocks/CU. Do NOT force
// min-waves: the unified VGPR+AGPR file makes <=64 regs infeasible for the
// 32-AGPR accumulator working set — R4/R6 spilled catastrophically.)
// LPT dispatch: long segments (big tt) first.
// ---------------------------------------------------------------------------
#define KVSZ (64 * 72)
#define SLOT_BYTES (16384 + 512)

__global__ __launch_bounds__(256) void attn_seg_kernel(
        const short* __restrict__ q, const short* __restrict__ k,
        const short* __restrict__ vt, float* __restrict__ slots) {
    __shared__ short ks[2 * KVSZ];
    __shared__ short vs[2 * KVSZ];
#if !defined(HAVE_MFMA16)
    __shared__ short ps[4 * 16 * 72];
#endif

    int nslot = gridDim.x;
    int b = blockIdx.y, fid = nslot - 1 - (int)blockIdx.x;   // LPT: long segments first
    int tt = 0, cum = 0;
    while (cum + ((2 * tt + 5) >> 2) <= fid) { cum += (2 * tt + 5) >> 2; tt++; }
    int nk = 2 * tt + 2;
    int k0 = (fid - cum) * 4;
    int k1 = min(k0 + 4, nk);

    int tid = threadIdx.x, w = tid >> 6, lane = tid & 63, quad = lane >> 4, l16 = lane & 15;
    int trow0 = tt * 128 + w * 32;

    short8 aq[2][2];
    for (int mt = 0; mt < 2; mt++) {
        const short* qrow = q + (size_t)(b * T_ + trow0 + mt * 16 + l16) * H_;
        aq[mt][0] = *(const short8*)&qrow[quad * 8];
        aq[mt][1] = *(const short8*)&qrow[32 + quad * 8];
    }

    floatx4 o[2][4];
    for (int mt = 0; mt < 2; mt++)
        for (int i = 0; i < 4; i++) o[mt][i] = (floatx4)0.0f;
    float lp[2] = {0.f, 0.f};

    const short* kb0 = k + (size_t)b * T_ * H_;
    const short* vtb = vt + (size_t)b * H_ * T_;

    int srow = tid >> 3, soff = (tid & 7) * 8;
    const float C1 = 0.125f * 1.44269504f;
    const float C2 = 12.0f * 1.44269504f;

    {   // preload first tile into buffer 0
        const short* kg = kb0 + (size_t)k0 * 64 * H_;
        const short* vg = vtb + k0 * 64;
        *(short8*)&ks[srow * 72 + soff] = *(const short8*)&kg[srow * H_ + soff];
        *(short8*)&ks[(srow + 32) * 72 + soff] = *(const short8*)&kg[(srow + 32) * H_ + soff];
        *(short8*)&vs[srow * 72 + soff] = *(const short8*)&vg[(size_t)srow * T_ + soff];
        *(short8*)&vs[(srow + 32) * 72 + soff] = *(const short8*)&vg[(size_t)(srow + 32) * T_ + soff];
    }
    __syncthreads();

    int p = 0;
    for (int st = k0; st < k1; st++) {
        bool more = (st + 1 < k1);
        short8 pk0, pk1, pv0, pv1;
        if (more) {
            const short* kg = kb0 + (size_t)(st + 1) * 64 * H_;
            const short* vg = vtb + (st + 1) * 64;
            pk0 = *(const short8*)&kg[srow * H_ + soff];
            pk1 = *(const short8*)&kg[(srow + 32) * H_ + soff];
            pv0 = *(const short8*)&vg[(size_t)srow * T_ + soff];
            pv1 = *(const short8*)&vg[(size_t)(srow + 32) * T_ + soff];
        }
        const short* ksp = ks + p * KVSZ;
        const short* vsp = vs + p * KVSZ;
        int s0 = st * 64;

        // S^T = K·Q^T : A = K-frag, B = Q-frag (operand swap).
        floatx4 sacc[2][4];
        for (int mt = 0; mt < 2; mt++)
            for (int nt = 0; nt < 4; nt++) sacc[mt][nt] = (floatx4)0.0f;
        __builtin_amdgcn_s_setprio(1);
        for (int nt = 0; nt < 4; nt++) {
            short8 bk0 = *(const short8*)&ksp[(nt * 16 + l16) * 72 + quad * 8];
            short8 bk1 = *(const short8*)&ksp[(nt * 16 + l16) * 72 + 32 + quad * 8];
            sacc[0][nt] = __builtin_amdgcn_mfma_f32_16x16x32_bf16(bk0, aq[0][0], sacc[0][nt], 0, 0, 0);
            sacc[0][nt] = __builtin_amdgcn_mfma_f32_16x16x32_bf16(bk1, aq[0][1], sacc[0][nt], 0, 0, 0);
            sacc[1][nt] = __builtin_amdgcn_mfma_f32_16x16x32_bf16(bk0, aq[1][0], sacc[1][nt], 0, 0, 0);
            sacc[1][nt] = __builtin_amdgcn_mfma_f32_16x16x32_bf16(bk1, aq[1][1], sacc[1][nt], 0, 0, 0);
        }
        __builtin_amdgcn_s_setprio(0);

        bool diag = (st >= 2 * tt);
#if defined(HAVE_MFMA16)
        short4_t pa[2][4];
        if (!diag) {            // wave-uniform fast path: no per-element mask
            for (int mt = 0; mt < 2; mt++) {
                float ts[4];
                for (int nt = 0; nt < 4; nt++) {
                    float pv[4];
                    for (int r = 0; r < 4; r++)
                        pv[r] = __builtin_amdgcn_exp2f(fmaf(sacc[mt][nt][r], C1, -C2));
                    uint2_t u;
                    u.x = cvt_pk_bf16(pv[0], pv[1]);
                    u.y = cvt_pk_bf16(pv[2], pv[3]);
                    pa[mt][nt] = __builtin_bit_cast(short4_t, u);
                    ts[nt] = (pv[0] + pv[1]) + (pv[2] + pv[3]);
                }
                lp[mt] += (ts[0] + ts[1]) + (ts[2] + ts[3]);
            }
        } else {
            for (int mt = 0; mt < 2; mt++) {
                int q_idx = trow0 + mt * 16 + l16;
                float ts[4];
                for (int nt = 0; nt < 4; nt++) {
                    float pv[4];
                    for (int r = 0; r < 4; r++) {
                        float pe = __builtin_amdgcn_exp2f(fmaf(sacc[mt][nt][r], C1, -C2));
                        int s_idx = s0 + nt * 16 + quad * 4 + r;
                        pv[r] = (s_idx > q_idx) ? 0.0f : pe;
                    }
                    uint2_t u;
                    u.x = cvt_pk_bf16(pv[0], pv[1]);
                    u.y = cvt_pk_bf16(pv[2], pv[3]);
                    pa[mt][nt] = __builtin_bit_cast(short4_t, u);
                    ts[nt] = (pv[0] + pv[1]) + (pv[2] + pv[3]);
                }
                lp[mt] += (ts[0] + ts[1]) + (ts[2] + ts[3]);
            }
        }
        // O += P·V : A = P (registers), B = V-frag, K=16 MFMA.
        __builtin_amdgcn_s_setprio(1);
        for (int nh = 0; nh < 4; nh++) {
            const short* vrow = &vsp[(nh * 16 + l16) * 72 + quad * 4];
            for (int c = 0; c < 4; c++) {
                short4_t bv = *(const short4_t*)&vrow[c * 16];
                o[0][nh] = __builtin_amdgcn_mfma_f32_16x16x16bf16_1k(pa[0][c], bv, o[0][nh], 0, 0, 0);
                o[1][nh] = __builtin_amdgcn_mfma_f32_16x16x16bf16_1k(pa[1][c], bv, o[1][nh], 0, 0, 0);
            }
        }
        __builtin_amdgcn_s_setprio(0);
#else
        short* psw = ps + w * 16 * 72;
        short8 ap[2][2];
        for (int mt = 0; mt < 2; mt++) {
            int q_idx = trow0 + mt * 16 + l16;
            for (int nt = 0; nt < 4; nt++)
                for (int r = 0; r < 4; r++) {
                    float pv = __builtin_amdgcn_exp2f(fmaf(sacc[mt][nt][r], C1, -C2));
                    int s_idx = s0 + nt * 16 + quad * 4 + r;
                    if (diag && (s_idx > q_idx)) pv = 0.0f;
                    lp[mt] += pv;
                    psw[l16 * 72 + nt * 16 + quad * 4 + r] = f2bf(pv);
                }
            ap[mt][0] = *(const short8*)&psw[l16 * 72 + quad * 8];
            ap[mt][1] = *(const short8*)&psw[l16 * 72 + 32 + quad * 8];
        }
        for (int nh = 0; nh < 4; nh++) {
            short8 bv0 = *(const short8*)&vsp[(nh * 16 + l16) * 72 + quad * 8];
            short8 bv1 = *(const short8*)&vsp[(nh * 16 + l16) * 72 + 32 + quad * 8];
            o[0][nh] = __builtin_amdgcn_mfma_f32_16x16x32_bf16(ap[0][0], bv0, o[0][nh], 0, 0, 0);
            o[0][nh] = __builtin_amdgcn_mfma_f32_16x16x32_bf16(ap[0][1], bv1, o[0][nh], 0, 0, 0);
            o[1][nh] = __builtin_amdgcn_mfma_f32_16x16x32_bf16(ap[1][0], bv0, o[1][nh], 0, 0, 0);
            o[1][nh] = __builtin_amdgcn_mfma_f32_16x16x32_bf16(ap[1][1], bv1, o[1][nh], 0, 0, 0);
        }
#endif

        if (more) {
            short* kd = ks + (1 - p) * KVSZ;
            short* vd = vs + (1 - p) * KVSZ;
            *(short8*)&kd[srow * 72 + soff] = pk0;
            *(short8*)&kd[(srow + 32) * 72 + soff] = pk1;
            *(short8*)&vd[srow * 72 + soff] = pv0;
            *(short8*)&vd[(srow + 32) * 72 + soff] = pv1;
            __syncthreads();
            p ^= 1;
        }
    }

    for (int mt = 0; mt < 2; mt++) {
        lp[mt] += __shfl_xor(lp[mt], 16);
        lp[mt] += __shfl_xor(lp[mt], 32);
    }

    char* slotb = (char*)slots + ((size_t)b * nslot + fid) * SLOT_BYTES;
    short* slotO = (short*)slotb;
    float* slotL = (float*)(slotb + 16384);

    for (int mt = 0; mt < 2; mt++)
        for (int nh = 0; nh < 4; nh++)
            for (int r = 0; r < 4; r += 2) {
                unsigned pk2 = cvt_pk_bf16(o[mt][nh][r], o[mt][nh][r + 1]);
                slotO[(w * 32 + mt * 16 + quad * 4 + r) * 64 + nh * 16 + l16] = (short)pk2;
                slotO[(w * 32 + mt * 16 + quad * 4 + r + 1) * 64 + nh * 16 + l16] = (short)(pk2 >> 16);
            }
    if (quad == 0)
        for (int mt = 0; mt < 2; mt++)
            slotL[w * 32 + mt * 16 + l16] = lp[mt];
}

// ---------------------------------------------------------------------------
// Kernel 2b: combine. 32-row blocks (grid T/32 x B = 1024 blocks).
// ---------------------------------------------------------------------------
__global__ __launch_bounds__(256) void combine_kernel(
        const float* __restrict__ slots, int nslot, float* __restrict__ out) {
    int b = blockIdx.y, tb = blockIdx.x;        // tb in [0, 64)
    int tt = tb >> 2;
    int nseg = (2 * tt + 5) >> 2;
    int cum = 0;
    for (int i = 0; i < tt; i++) cum += (2 * i + 5) >> 2;
    const char* base = (const char*)slots + ((size_t)b * nslot + cum) * SLOT_BYTES;

    int tid = threadIdx.x;
    int row = (tb & 3) * 32 + (tid >> 3);       // row within the 128-row tile
    int qo = (tid & 7) * 8;                     // 8 columns per thread
    float acc[8];
    for (int i = 0; i < 8; i++) acc[i] = 0.f;
    float lsum = 0.f;
    for (int s = 0; s < nseg; s++) {
        const short* O = (const short*)(base + (size_t)s * SLOT_BYTES);
        const float* L = (const float*)(base + (size_t)s * SLOT_BYTES + 16384);
        short8 v = *(const short8*)&O[row * 64 + qo];
        uintx4 u = __builtin_bit_cast(uintx4, v);
        for (int j = 0; j < 4; j++) {
            acc[2 * j]     += __builtin_bit_cast(float, u[j] << 16);
            acc[2 * j + 1] += __builtin_bit_cast(float, u[j] & 0xFFFF0000u);
        }
        lsum += L[row];
    }
    float inv = 1.0f / lsum;
    float* op = out + (size_t)(b * T_ + tt * 128 + row) * H_ + qo;
    for (int i = 0; i < 2; i++) {
        float4 v;
        v.x = acc[i * 4 + 0] * inv; v.y = acc[i * 4 + 1] * inv;
        v.z = acc[i * 4 + 2] * inv; v.w = acc[i * 4 + 3] * inv;
        *(float4*)&op[i * 4] = v;
    }
}

// ---------------------------------------------------------------------------
// Fallback direct attention (used only if ws too small) — unchanged.
// ---------------------------------------------------------------------------
template<bool DIAG>
static __device__ __forceinline__ void attn_step(
        int s0, int t0w, int quad, int l16,
        const short* __restrict__ kbase, const short* __restrict__ vtb,
        short8 aq0, short8 aq1, short* __restrict__ psw,
        floatx4 (&o)[4], float (&lpart)[4]) {
    floatx4 sacc[4];
    for (int nt = 0; nt < 4; nt++) sacc[nt] = (floatx4)0.0f;
    for (int nt = 0; nt < 4; nt++) {
        short8 bk0 = *(const short8*)&kbase[(nt * 16 + l16) * H_ + quad * 8];
        short8 bk1 = *(const short8*)&kbase[(nt * 16 + l16) * H_ + 32 + quad * 8];
        sacc[nt] = __builtin_amdgcn_mfma_f32_16x16x32_bf16(aq0, bk0, sacc[nt], 0, 0, 0);
        sacc[nt] = __builtin_amdgcn_mfma_f32_16x16x32_bf16(aq1, bk1, sacc[nt], 0, 0, 0);
    }
    const float C1 = 0.125f * 1.44269504f;
    const float C2 = 12.0f * 1.44269504f;
    for (int nt = 0; nt < 4; nt++) {
        int s_idx = s0 + nt * 16 + l16;
        for (int r = 0; r < 4; r++) {
            float p = __builtin_amdgcn_exp2f(fmaf(sacc[nt][r], C1, -C2));
            if (DIAG && (s_idx > t0w + quad * 4 + r)) p = 0.0f;
            lpart[r] += p;
            psw[(quad * 4 + r) * 72 + nt * 16 + l16] = f2bf(p);
        }
    }
    short8 ap0 = *(const short8*)&psw[l16 * 72 + quad * 8];
    short8 ap1 = *(const short8*)&psw[l16 * 72 + 32 + quad * 8];
    for (int nh = 0; nh < 4; nh++) {
        short8 bv0 = *(const short8*)&vtb[(size_t)(nh * 16 + l16) * T_ + s0 + quad * 8];
        short8 bv1 = *(const short8*)&vtb[(size_t)(nh * 16 + l16) * T_ + s0 + 32 + quad * 8];
        o[nh] = __builtin_amdgcn_mfma_f32_16x16x32_bf16(ap0, bv0, o[nh], 0, 0, 0);
        o[nh] = __builtin_amdgcn_mfma_f32_16x16x32_bf16(ap1, bv1, o[nh], 0, 0, 0);
    }
}

__global__ __launch_bounds__(256) void attn_kernel(
        const short* __restrict__ q, const short* __restrict__ k,
        const short* __restrict__ vt, float* __restrict__ out) {
    __shared__ short ps[4 * 16 * 72];

    int b = blockIdx.y;
    int g = ((int)blockIdx.x + 4 * (b & 7)) & 31;
    int tt = (b < 8) ? g : 31 - g;
    int t0 = tt * 64;
    int tid = threadIdx.x, w = tid >> 6, lane = tid & 63, quad = lane >> 4, l16 = lane & 15;
    int t0w = t0 + w * 16;

    const short* qrow = q + (size_t)(b * T_ + t0w + l16) * H_;
    short8 aq0 = *(const short8*)&qrow[quad * 8];
    short8 aq1 = *(const short8*)&qrow[32 + quad * 8];

    floatx4 o[4];
    for (int nh = 0; nh < 4; nh++) o[nh] = (floatx4)0.0f;
    float lpart[4] = {0.f, 0.f, 0.f, 0.f};

    const short* kb0 = k + (size_t)b * T_ * H_;
    const short* vtb = vt + (size_t)b * H_ * T_;
    short* psw = ps + w * 16 * 72;

    for (int st = 0; st < tt; st++)
        attn_step<false>(st * 64, t0w, quad, l16, kb0 + (size_t)st * 64 * H_,
                         vtb, aq0, aq1, psw, o, lpart);
    attn_step<true>(tt * 64, t0w, quad, l16, kb0 + (size_t)tt * 64 * H_,
                    vtb, aq0, aq1, psw, o, lpart);

    for (int d = 1; d < 16; d <<= 1)
        for (int r = 0; r < 4; r++)
            lpart[r] += __shfl_xor(lpart[r], d, 16);

    for (int nh = 0; nh < 4; nh++)
        for (int r = 0; r < 4; r++) {
            int t = t0w + quad * 4 + r;
            out[(size_t)(b * T_ + t) * H_ + nh * 16 + l16] = o[nh][r] / lpart[r];
        }
}

// ---------------------------------------------------------------------------
extern "C" void kernel_launch(void* const* d_in, const int* in_sizes, int n_in,
                              void* d_out, int out_size, void* d_ws, size_t ws_size,
                              hipStream_t stream) {
    const float* x  = (const float*)d_in[0];
    const float* Wq = (const float*)d_in[1];
    const float* Wk = (const float*)d_in[2];
    const float* Wv = (const float*)d_in[3];

    char* ws = (char*)d_ws;
    short* qb  = (short*)(ws);                                  // 4 MB
    short* kb  = (short*)(ws + (size_t)4 * 1024 * 1024);        // 4 MB
    short* vtb = (short*)(ws + (size_t)8 * 1024 * 1024);        // 4 MB, [B][H][T]
    short* wtb = (short*)(ws + (size_t)12 * 1024 * 1024);       // 144 KB (frag order)
    float* slots = (float*)(ws + (size_t)12 * 1024 * 1024 + 256 * 1024);
    size_t base_need = (size_t)12 * 1024 * 1024 + 256 * 1024;

    wt_kernel<<<dim3(288), dim3(256), 0, stream>>>(Wq, Wk, Wv, wtb);
    qkv_kernel<<<dim3(T_ / 64, B_), dim3(256), 0, stream>>>(x, wtb, qb, kb, vtb);

    float* out = (float*)d_out;
    const int NSLOT = 72;   // sum_{tt=0}^{15} ceil((2tt+2)/4)
    if (ws_size >= base_need + (size_t)B_ * NSLOT * (size_t)SLOT_BYTES) {
        attn_seg_kernel<<<dim3(NSLOT, B_), dim3(256), 0, stream>>>(qb, kb, vtb, slots);
        combine_kernel<<<dim3(T_ / 32, B_), dim3(256), 0, stream>>>(slots, NSLOT, out);
    } else {
        attn_kernel<<<dim3(T_ / 64, B_), dim3(256), 0, stream>>>(qb, kb, vtb, out);
    }
}